// Round 8
// baseline (676.724 us; speedup 1.0000x reference)
//
#include <hip/hip_runtime.h>
#include <stdint.h>

#define NN    100000
#define FIN   128
#define HIDN  64
#define NCLS  40
#define NE    1600000
#define NBUCK ((NN + 255) / 256)      // 391 buckets of 256 nodes
#define EPB   4096                    // edges per partition block
#define NEB   ((NE + EPB - 1) / EPB)  // 391 partition blocks

typedef unsigned int uint32;

static __device__ __forceinline__ unsigned short f2bf(float f) {
  uint32 u = __float_as_uint(f);
  u = (u + 0x7fffu + ((u >> 16) & 1u)) >> 16;   // RNE
  return (unsigned short)u;
}
static __device__ __forceinline__ uint32 pack2(float lo, float hi) {
  return (uint32)f2bf(lo) | ((uint32)f2bf(hi) << 16);
}
static __device__ __forceinline__ float bf_lo(uint32 v) {
  return __uint_as_float(v << 16);
}
static __device__ __forceinline__ float bf_hi(uint32 v) {
  return __uint_as_float(v & 0xFFFF0000u);
}

// ---- edge dtype probe: int64 (odd u32 words all zero) vs int32 ----
__global__ __launch_bounds__(64) void probe_kernel(const unsigned int* __restrict__ raw,
                                                   int* __restrict__ flag) {
  if (threadIdx.x == 0) {
    int is64 = 1;
    for (int i = 0; i < 64; ++i)
      if (raw[2 * i + 1] != 0u) { is64 = 0; break; }
    *flag = is64;
  }
}

// ---- passA: per-block bucket histogram -> mat[blk][bucket] ----
__global__ __launch_bounds__(256) void passA_kernel(const void* __restrict__ eptr,
                                                    const int* __restrict__ flag,
                                                    int* __restrict__ mat) {
  __shared__ int cnt[NBUCK];
  int tid = threadIdx.x;
  for (int i = tid; i < NBUCK; i += 256) cnt[i] = 0;
  __syncthreads();
  int is64 = *flag;
  int base = blockIdx.x * EPB;
#pragma unroll
  for (int k = 0; k < EPB / 256; ++k) {
    int e = base + k * 256 + tid;
    if (e < NE) {
      int d = is64 ? (int)((const long long*)eptr)[e + NE]
                   : ((const int*)eptr)[e + NE];
      atomicAdd(&cnt[d >> 8], 1);
    }
  }
  __syncthreads();
  for (int i = tid; i < NBUCK; i += 256)
    mat[blockIdx.x * NBUCK + i] = cnt[i];
}

// ---- passB1: per-bucket exclusive scan over blocks; emit bucket totals ----
__global__ __launch_bounds__(512) void passB1_kernel(int* __restrict__ mat,
                                                     int* __restrict__ tot) {
  __shared__ int s[512];
  int b = blockIdx.x;         // bucket
  int t = threadIdx.x;        // block index
  int v = (t < NEB) ? mat[t * NBUCK + b] : 0;
  s[t] = v;
  __syncthreads();
#pragma unroll
  for (int d = 1; d < 512; d <<= 1) {
    int u = (t >= d) ? s[t - d] : 0;
    __syncthreads();
    s[t] += u;
    __syncthreads();
  }
  if (t < NEB) mat[t * NBUCK + b] = s[t] - v;  // exclusive prefix within bucket
  if (t == 511) tot[b] = s[511];
}

// ---- passB2: exclusive scan of bucket totals -> bbase ----
__global__ __launch_bounds__(512) void passB2_kernel(const int* __restrict__ tot,
                                                     int* __restrict__ bbase) {
  __shared__ int s[512];
  int i = threadIdx.x;
  int v = (i < NBUCK) ? tot[i] : 0;
  s[i] = v;
  __syncthreads();
#pragma unroll
  for (int d = 1; d < 512; d <<= 1) {
    int u = (i >= d) ? s[i - d] : 0;
    __syncthreads();
    s[i] += u;
    __syncthreads();
  }
  if (i < NBUCK) bbase[i] = s[i] - v;
  if (i == 511) bbase[NBUCK] = s[511];
}

// ---- passC: place edges into compact bucket-sorted bbuf (LDS cursors) ----
__global__ __launch_bounds__(256) void passC_kernel(const void* __restrict__ eptr,
                                                    const int* __restrict__ flag,
                                                    const int* __restrict__ mat,
                                                    const int* __restrict__ bbase,
                                                    uint32* __restrict__ bbuf) {
  __shared__ int cur[NBUCK];
  int tid = threadIdx.x;
  for (int i = tid; i < NBUCK; i += 256)
    cur[i] = bbase[i] + mat[blockIdx.x * NBUCK + i];
  __syncthreads();
  int is64 = *flag;
  int base = blockIdx.x * EPB;
#pragma unroll
  for (int k = 0; k < EPB / 256; ++k) {
    int e = base + k * 256 + tid;
    if (e < NE) {
      int s, d;
      if (is64) {
        const long long* p = (const long long*)eptr;
        s = (int)p[e]; d = (int)p[e + NE];
      } else {
        const int* p = (const int*)eptr;
        s = p[e]; d = p[e + NE];
      }
      int slot = atomicAdd(&cur[d >> 8], 1);
      bbuf[slot] = (uint32)s | ((uint32)(d & 255) << 17);
    }
  }
}

// ---- build: per-bucket CSR (LDS hist + scan + rank placement) ----
__global__ __launch_bounds__(256) void build_kernel(const int* __restrict__ bbase,
                                                    const uint32* __restrict__ bbuf,
                                                    int* __restrict__ off,
                                                    float* __restrict__ dinv,
                                                    int* __restrict__ s_src) {
  __shared__ int hist[256];
  __shared__ int lofs[256];
  __shared__ int rank[256];
  int b = blockIdx.x, tid = threadIdx.x;
  int base = bbase[b];
  int count = bbase[b + 1] - base;
  const uint32* p = bbuf + base;
  hist[tid] = 0;
  __syncthreads();
  for (int i = tid; i < count; i += 256) atomicAdd(&hist[p[i] >> 17], 1);
  __syncthreads();
  int deg = hist[tid];
  lofs[tid] = deg;
  __syncthreads();
#pragma unroll
  for (int dd = 1; dd < 256; dd <<= 1) {
    int t = (tid >= dd) ? lofs[tid - dd] : 0;
    __syncthreads();
    lofs[tid] += t;
    __syncthreads();
  }
  int excl = lofs[tid] - deg;
  __syncthreads();
  lofs[tid] = excl;
  rank[tid] = 0;
  int n = b * 256 + tid;
  if (n < NN) {
    off[n] = base + excl;
    dinv[n] = rsqrtf((float)deg + 1.0f);
  }
  if (b == 0 && tid == 0) off[NN] = NE;
  __syncthreads();
  for (int i = tid; i < count; i += 256) {
    uint32 v = p[i];
    int dl = (int)(v >> 17);
    int s = (int)(v & 0x1FFFFu);
    int r = atomicAdd(&rank[dl], 1);
    s_src[base + lofs[dl] + r] = s;
  }
}

// ---- GEMM1: hs[N,64](bf16) = (x[N,128] @ W1[128,64]) * dinv[row] ----
__global__ __launch_bounds__(256) void gemm1_kernel(const float* __restrict__ x,
                                                    const float* __restrict__ W,
                                                    const float* __restrict__ dinv,
                                                    uint32* __restrict__ hs) {
  __shared__ float sW[FIN * HIDN];  // 32 KB
  int tid = threadIdx.x;
  {
    const float4* W4 = (const float4*)W;
    float4* sW4 = (float4*)sW;
#pragma unroll
    for (int i = 0; i < 8; ++i) sW4[i * 256 + tid] = W4[i * 256 + tid];
  }
  __syncthreads();
  int cg = tid & 3;
  int rp = tid >> 2;
  int r0 = blockIdx.x * 128 + rp * 2;
  int r1 = r0 + 1;
  bool v0 = (r0 < NN), v1 = (r1 < NN);
  int c0 = cg * 16;
  float4 a0[4], a1[4];
#pragma unroll
  for (int j = 0; j < 4; ++j) {
    a0[j] = make_float4(0.f, 0.f, 0.f, 0.f);
    a1[j] = make_float4(0.f, 0.f, 0.f, 0.f);
  }
  const float4* x4 = (const float4*)x;
  const float4 z4 = make_float4(0.f, 0.f, 0.f, 0.f);
  for (int k0 = 0; k0 < FIN; k0 += 4) {
    float4 xa = v0 ? x4[(size_t)r0 * 32 + (k0 >> 2)] : z4;
    float4 xb = v1 ? x4[(size_t)r1 * 32 + (k0 >> 2)] : z4;
#pragma unroll
    for (int kk = 0; kk < 4; ++kk) {
      float xav = (&xa.x)[kk];
      float xbv = (&xb.x)[kk];
      int k = k0 + kk;
#pragma unroll
      for (int j = 0; j < 4; ++j) {
        float4 wv = *(const float4*)&sW[k * HIDN + c0 + 4 * j];
        a0[j].x += xav * wv.x; a0[j].y += xav * wv.y;
        a0[j].z += xav * wv.z; a0[j].w += xav * wv.w;
        a1[j].x += xbv * wv.x; a1[j].y += xbv * wv.y;
        a1[j].z += xbv * wv.z; a1[j].w += xbv * wv.w;
      }
    }
  }
  if (v0) {
    float di = dinv[r0];
    uint4 q0, q1;
    q0.x = pack2(a0[0].x * di, a0[0].y * di); q0.y = pack2(a0[0].z * di, a0[0].w * di);
    q0.z = pack2(a0[1].x * di, a0[1].y * di); q0.w = pack2(a0[1].z * di, a0[1].w * di);
    q1.x = pack2(a0[2].x * di, a0[2].y * di); q1.y = pack2(a0[2].z * di, a0[2].w * di);
    q1.z = pack2(a0[3].x * di, a0[3].y * di); q1.w = pack2(a0[3].z * di, a0[3].w * di);
    uint4* hp = (uint4*)&hs[(size_t)r0 * 32 + cg * 8];
    hp[0] = q0; hp[1] = q1;
  }
  if (v1) {
    float di = dinv[r1];
    uint4 q0, q1;
    q0.x = pack2(a1[0].x * di, a1[0].y * di); q0.y = pack2(a1[0].z * di, a1[0].w * di);
    q0.z = pack2(a1[1].x * di, a1[1].y * di); q0.w = pack2(a1[1].z * di, a1[1].w * di);
    q1.x = pack2(a1[2].x * di, a1[2].y * di); q1.y = pack2(a1[2].z * di, a1[2].w * di);
    q1.z = pack2(a1[3].x * di, a1[3].y * di); q1.w = pack2(a1[3].z * di, a1[3].w * di);
    uint4* hp = (uint4*)&hs[(size_t)r1 * 32 + cg * 8];
    hp[0] = q0; hp[1] = q1;
  }
}

// ---- agg1: 16 lanes/edge, 4 edges/wave, unroll x2 -> 8 gathers in flight.
// g[n] = bf16( dinv_n * relu( dinv_n*(hs[n]+sum_j hs[s_j]) + b1 ) ) ----
__global__ __launch_bounds__(256) void agg1_kernel(const int* __restrict__ off,
                                                   const int* __restrict__ s_src,
                                                   const uint2* __restrict__ hs2,
                                                   const float* __restrict__ dinv,
                                                   const float* __restrict__ b1,
                                                   uint2* __restrict__ g) {
  int n = blockIdx.x * 4 + (threadIdx.x >> 6);     // NN = 25000*4 exactly
  int lane = threadIdx.x & 63;
  int q = lane >> 4;           // edge slot 0..3
  int hc = lane & 15;          // 4-col group (cols 4hc..4hc+3)
  int j0 = off[n], j1 = off[n + 1];
  float ax = 0.f, ay = 0.f, az = 0.f, aw = 0.f;
  if (q == 0) {
    uint2 v = hs2[(size_t)n * 16 + hc];
    ax = bf_lo(v.x); ay = bf_hi(v.x); az = bf_lo(v.y); aw = bf_hi(v.y);
  }
  int j = j0 + q;
  for (; j + 4 < j1; j += 8) {
    int sa = s_src[j], sb = s_src[j + 4];
    uint2 va = hs2[(size_t)sa * 16 + hc];
    uint2 vb = hs2[(size_t)sb * 16 + hc];
    ax += bf_lo(va.x); ay += bf_hi(va.x); az += bf_lo(va.y); aw += bf_hi(va.y);
    ax += bf_lo(vb.x); ay += bf_hi(vb.x); az += bf_lo(vb.y); aw += bf_hi(vb.y);
  }
  if (j < j1) {
    int sa = s_src[j];
    uint2 va = hs2[(size_t)sa * 16 + hc];
    ax += bf_lo(va.x); ay += bf_hi(va.x); az += bf_lo(va.y); aw += bf_hi(va.y);
  }
  ax += __shfl_xor(ax, 16, 64); ay += __shfl_xor(ay, 16, 64);
  az += __shfl_xor(az, 16, 64); aw += __shfl_xor(aw, 16, 64);
  ax += __shfl_xor(ax, 32, 64); ay += __shfl_xor(ay, 32, 64);
  az += __shfl_xor(az, 32, 64); aw += __shfl_xor(aw, 32, 64);
  if (q == 0) {
    float di = dinv[n];
    float4 bb = *(const float4*)&b1[hc * 4];
    float vx = di * fmaxf(ax * di + bb.x, 0.f);
    float vy = di * fmaxf(ay * di + bb.y, 0.f);
    float vz = di * fmaxf(az * di + bb.z, 0.f);
    float vw = di * fmaxf(aw * di + bb.w, 0.f);
    uint2 o;
    o.x = pack2(vx, vy);
    o.y = pack2(vz, vw);
    g[(size_t)n * 16 + hc] = o;   // 16 lanes x 8 B = 128 B contiguous
  }
}

// ---- agg2: same gather shape on g; t[n] = dinv_n*(g[n]+sum_j g[s_j]) (fp32) ----
__global__ __launch_bounds__(256) void agg2_kernel(const int* __restrict__ off,
                                                   const int* __restrict__ s_src,
                                                   const uint2* __restrict__ g,
                                                   const float* __restrict__ dinv,
                                                   float* __restrict__ t) {
  int n = blockIdx.x * 4 + (threadIdx.x >> 6);
  int lane = threadIdx.x & 63;
  int q = lane >> 4;
  int hc = lane & 15;
  int j0 = off[n], j1 = off[n + 1];
  float ax = 0.f, ay = 0.f, az = 0.f, aw = 0.f;
  if (q == 0) {
    uint2 v = g[(size_t)n * 16 + hc];
    ax = bf_lo(v.x); ay = bf_hi(v.x); az = bf_lo(v.y); aw = bf_hi(v.y);
  }
  int j = j0 + q;
  for (; j + 4 < j1; j += 8) {
    int sa = s_src[j], sb = s_src[j + 4];
    uint2 va = g[(size_t)sa * 16 + hc];
    uint2 vb = g[(size_t)sb * 16 + hc];
    ax += bf_lo(va.x); ay += bf_hi(va.x); az += bf_lo(va.y); aw += bf_hi(va.y);
    ax += bf_lo(vb.x); ay += bf_hi(vb.x); az += bf_lo(vb.y); aw += bf_hi(vb.y);
  }
  if (j < j1) {
    int sa = s_src[j];
    uint2 va = g[(size_t)sa * 16 + hc];
    ax += bf_lo(va.x); ay += bf_hi(va.x); az += bf_lo(va.y); aw += bf_hi(va.y);
  }
  ax += __shfl_xor(ax, 16, 64); ay += __shfl_xor(ay, 16, 64);
  az += __shfl_xor(az, 16, 64); aw += __shfl_xor(aw, 16, 64);
  ax += __shfl_xor(ax, 32, 64); ay += __shfl_xor(ay, 32, 64);
  az += __shfl_xor(az, 32, 64); aw += __shfl_xor(aw, 32, 64);
  if (q == 0) {
    float di = dinv[n];
    float4 o = make_float4(ax * di, ay * di, az * di, aw * di);
    *(float4*)&t[(size_t)n * HIDN + hc * 4] = o;  // 16 lanes x 16 B = 256 B
  }
}

// ---- gemm_out: out[N,40] = t[N,64] @ W2[64,40] + b2 ----
__global__ __launch_bounds__(320) void gemm_out_kernel(const float* __restrict__ t,
                                                       const float* __restrict__ W2,
                                                       const float* __restrict__ b2,
                                                       float* __restrict__ out) {
  __shared__ float sW[HIDN * NCLS];  // 10 KB
  int tid = threadIdx.x;
  for (int i = tid; i < (HIDN * NCLS) / 4; i += 320)
    ((float4*)sW)[i] = ((const float4*)W2)[i];
  __syncthreads();
  int cg = tid % 10;
  int rp = tid / 10;
  int r0 = blockIdx.x * 64 + rp * 2;
  int r1 = r0 + 1;
  bool v0 = (r0 < NN), v1 = (r1 < NN);
  int c0 = cg * 4;
  float4 a0 = make_float4(0.f, 0.f, 0.f, 0.f);
  float4 a1 = make_float4(0.f, 0.f, 0.f, 0.f);
  const float4* g4 = (const float4*)t;
  const float4 z4 = make_float4(0.f, 0.f, 0.f, 0.f);
  for (int k0 = 0; k0 < HIDN; k0 += 4) {
    float4 xa = v0 ? g4[(size_t)r0 * 16 + (k0 >> 2)] : z4;
    float4 xb = v1 ? g4[(size_t)r1 * 16 + (k0 >> 2)] : z4;
#pragma unroll
    for (int kk = 0; kk < 4; ++kk) {
      float xav = (&xa.x)[kk];
      float xbv = (&xb.x)[kk];
      float4 wv = *(const float4*)&sW[(k0 + kk) * NCLS + c0];
      a0.x += xav * wv.x; a0.y += xav * wv.y; a0.z += xav * wv.z; a0.w += xav * wv.w;
      a1.x += xbv * wv.x; a1.y += xbv * wv.y; a1.z += xbv * wv.z; a1.w += xbv * wv.w;
    }
  }
  float4 bb = *(const float4*)&b2[c0];
  if (v0) {
    a0.x += bb.x; a0.y += bb.y; a0.z += bb.z; a0.w += bb.w;
    *(float4*)&out[(size_t)r0 * NCLS + c0] = a0;
  }
  if (v1) {
    a1.x += bb.x; a1.y += bb.y; a1.z += bb.z; a1.w += bb.w;
    *(float4*)&out[(size_t)r1 * NCLS + c0] = a1;
  }
}

extern "C" void kernel_launch(void* const* d_in, const int* in_sizes, int n_in,
                              void* d_out, int out_size, void* d_ws, size_t ws_size,
                              hipStream_t stream) {
  const float* x  = (const float*)d_in[0];
  const void*  ei = d_in[1];
  const float* W1 = (const float*)d_in[2];
  const float* b1 = (const float*)d_in[3];
  const float* W2 = (const float*)d_in[4];
  const float* b2 = (const float*)d_in[5];
  float* out = (float*)d_out;

  char* w = (char*)d_ws;
  size_t off_b = 0;
  auto carve = [&](size_t bytes) -> void* {
    void* p = w + off_b;
    off_b = (off_b + bytes + 255) & ~(size_t)255;
    return p;
  };
  int*    mat   = (int*)   carve((size_t)NEB * NBUCK * 4);   // 611 KB
  int*    tot   = (int*)   carve((size_t)NBUCK * 4);
  int*    bbase = (int*)   carve((size_t)(NBUCK + 1) * 4);
  int*    offs  = (int*)   carve((size_t)(NN + 1) * 4);
  float*  dinv  = (float*) carve((size_t)NN * 4);
  int*    flag  = (int*)   carve(256);
  int*    s_src = (int*)   carve((size_t)NE * 4);
  uint32* hs    = (uint32*)carve((size_t)NN * 32 * 4);       // bf16 h, 12.8 MB
  uint2*  g     = (uint2*) carve((size_t)NN * 16 * 8);       // bf16 g, 12.8 MB
  float*  t     = (float*) carve((size_t)NN * HIDN * 4);     // fp32, 25.6 MB
  // alias: bbuf (compact, NE*4 = 6.4 MB) lives in t's region (bbuf dead after
  // build; t first written by agg2, long after build)
  uint32* bbuf = (uint32*)t;

  probe_kernel<<<1, 64, 0, stream>>>((const unsigned int*)ei, flag);
  passA_kernel<<<NEB, 256, 0, stream>>>(ei, flag, mat);
  passB1_kernel<<<NBUCK, 512, 0, stream>>>(mat, tot);
  passB2_kernel<<<1, 512, 0, stream>>>(tot, bbase);
  passC_kernel<<<NEB, 256, 0, stream>>>(ei, flag, mat, bbase, bbuf);
  build_kernel<<<NBUCK, 256, 0, stream>>>(bbase, bbuf, offs, dinv, s_src);
  gemm1_kernel<<<(NN + 127) / 128, 256, 0, stream>>>(x, W1, dinv, hs);
  agg1_kernel<<<NN / 4, 256, 0, stream>>>(offs, s_src, (const uint2*)hs, dinv, b1, g);
  agg2_kernel<<<NN / 4, 256, 0, stream>>>(offs, s_src, g, dinv, t);
  gemm_out_kernel<<<(NN + 63) / 64, 320, 0, stream>>>(t, W2, b2, out);
}

// Round 9
// 293.525 us; speedup vs baseline: 2.3055x; 2.3055x over previous
//
#include <hip/hip_runtime.h>
#include <stdint.h>

#define NN    100000
#define FIN   128
#define HIDN  64
#define NCLS  40
#define NE    1600000
#define NBUCK ((NN + 255) / 256)      // 391 buckets of 256 nodes
#define EPB   4096                    // edges per partition block
#define NEB   ((NE + EPB - 1) / EPB)  // 391 partition blocks

typedef unsigned int uint32;

static __device__ __forceinline__ unsigned short f2bf(float f) {
  uint32 u = __float_as_uint(f);
  u = (u + 0x7fffu + ((u >> 16) & 1u)) >> 16;   // RNE
  return (unsigned short)u;
}
static __device__ __forceinline__ uint32 pack2(float lo, float hi) {
  return (uint32)f2bf(lo) | ((uint32)f2bf(hi) << 16);
}
static __device__ __forceinline__ float bf_lo(uint32 v) {
  return __uint_as_float(v << 16);
}
static __device__ __forceinline__ float bf_hi(uint32 v) {
  return __uint_as_float(v & 0xFFFF0000u);
}

// ---- edge dtype probe: int64 (odd u32 words all zero) vs int32 ----
__global__ __launch_bounds__(64) void probe_kernel(const unsigned int* __restrict__ raw,
                                                   int* __restrict__ flag) {
  if (threadIdx.x == 0) {
    int is64 = 1;
    for (int i = 0; i < 64; ++i)
      if (raw[2 * i + 1] != 0u) { is64 = 0; break; }
    *flag = is64;
  }
}

// ---- passA: per-block bucket histogram -> mat[blk][bucket] ----
__global__ __launch_bounds__(256) void passA_kernel(const void* __restrict__ eptr,
                                                    const int* __restrict__ flag,
                                                    int* __restrict__ mat) {
  __shared__ int cnt[NBUCK];
  int tid = threadIdx.x;
  for (int i = tid; i < NBUCK; i += 256) cnt[i] = 0;
  __syncthreads();
  int is64 = *flag;
  int base = blockIdx.x * EPB;
#pragma unroll
  for (int k = 0; k < EPB / 256; ++k) {
    int e = base + k * 256 + tid;
    if (e < NE) {
      int d = is64 ? (int)((const long long*)eptr)[e + NE]
                   : ((const int*)eptr)[e + NE];
      atomicAdd(&cnt[d >> 8], 1);
    }
  }
  __syncthreads();
  for (int i = tid; i < NBUCK; i += 256)
    mat[blockIdx.x * NBUCK + i] = cnt[i];
}

// ---- passB1: per-bucket exclusive scan over blocks; emit bucket totals ----
__global__ __launch_bounds__(512) void passB1_kernel(int* __restrict__ mat,
                                                     int* __restrict__ tot) {
  __shared__ int s[512];
  int b = blockIdx.x;         // bucket
  int t = threadIdx.x;        // block index
  int v = (t < NEB) ? mat[t * NBUCK + b] : 0;
  s[t] = v;
  __syncthreads();
#pragma unroll
  for (int d = 1; d < 512; d <<= 1) {
    int u = (t >= d) ? s[t - d] : 0;
    __syncthreads();
    s[t] += u;
    __syncthreads();
  }
  if (t < NEB) mat[t * NBUCK + b] = s[t] - v;  // exclusive prefix within bucket
  if (t == 511) tot[b] = s[511];
}

// ---- passB2: exclusive scan of bucket totals -> bbase ----
__global__ __launch_bounds__(512) void passB2_kernel(const int* __restrict__ tot,
                                                     int* __restrict__ bbase) {
  __shared__ int s[512];
  int i = threadIdx.x;
  int v = (i < NBUCK) ? tot[i] : 0;
  s[i] = v;
  __syncthreads();
#pragma unroll
  for (int d = 1; d < 512; d <<= 1) {
    int u = (i >= d) ? s[i - d] : 0;
    __syncthreads();
    s[i] += u;
    __syncthreads();
  }
  if (i < NBUCK) bbase[i] = s[i] - v;
  if (i == 511) bbase[NBUCK] = s[511];
}

// ---- passC: place edges into compact bucket-sorted bbuf (LDS cursors) ----
__global__ __launch_bounds__(256) void passC_kernel(const void* __restrict__ eptr,
                                                    const int* __restrict__ flag,
                                                    const int* __restrict__ mat,
                                                    const int* __restrict__ bbase,
                                                    uint32* __restrict__ bbuf) {
  __shared__ int cur[NBUCK];
  int tid = threadIdx.x;
  for (int i = tid; i < NBUCK; i += 256)
    cur[i] = bbase[i] + mat[blockIdx.x * NBUCK + i];
  __syncthreads();
  int is64 = *flag;
  int base = blockIdx.x * EPB;
#pragma unroll
  for (int k = 0; k < EPB / 256; ++k) {
    int e = base + k * 256 + tid;
    if (e < NE) {
      int s, d;
      if (is64) {
        const long long* p = (const long long*)eptr;
        s = (int)p[e]; d = (int)p[e + NE];
      } else {
        const int* p = (const int*)eptr;
        s = p[e]; d = p[e + NE];
      }
      int slot = atomicAdd(&cur[d >> 8], 1);
      bbuf[slot] = (uint32)s | ((uint32)(d & 255) << 17);
    }
  }
}

// ---- build: per-bucket CSR (LDS hist + scan + rank placement) ----
__global__ __launch_bounds__(256) void build_kernel(const int* __restrict__ bbase,
                                                    const uint32* __restrict__ bbuf,
                                                    int* __restrict__ off,
                                                    float* __restrict__ dinv,
                                                    int* __restrict__ s_src) {
  __shared__ int hist[256];
  __shared__ int lofs[256];
  __shared__ int rank[256];
  int b = blockIdx.x, tid = threadIdx.x;
  int base = bbase[b];
  int count = bbase[b + 1] - base;
  const uint32* p = bbuf + base;
  hist[tid] = 0;
  __syncthreads();
  for (int i = tid; i < count; i += 256) atomicAdd(&hist[p[i] >> 17], 1);
  __syncthreads();
  int deg = hist[tid];
  lofs[tid] = deg;
  __syncthreads();
#pragma unroll
  for (int dd = 1; dd < 256; dd <<= 1) {
    int t = (tid >= dd) ? lofs[tid - dd] : 0;
    __syncthreads();
    lofs[tid] += t;
    __syncthreads();
  }
  int excl = lofs[tid] - deg;
  __syncthreads();
  lofs[tid] = excl;
  rank[tid] = 0;
  int n = b * 256 + tid;
  if (n < NN) {
    off[n] = base + excl;
    dinv[n] = rsqrtf((float)deg + 1.0f);
  }
  if (b == 0 && tid == 0) off[NN] = NE;
  __syncthreads();
  for (int i = tid; i < count; i += 256) {
    uint32 v = p[i];
    int dl = (int)(v >> 17);
    int s = (int)(v & 0x1FFFFu);
    int r = atomicAdd(&rank[dl], 1);
    s_src[base + lofs[dl] + r] = s;
  }
}

// ---- GEMM1: hs[N,64](bf16) = (x[N,128] @ W1[128,64]) * dinv[row] ----
__global__ __launch_bounds__(256) void gemm1_kernel(const float* __restrict__ x,
                                                    const float* __restrict__ W,
                                                    const float* __restrict__ dinv,
                                                    uint32* __restrict__ hs) {
  __shared__ float sW[FIN * HIDN];  // 32 KB
  int tid = threadIdx.x;
  {
    const float4* W4 = (const float4*)W;
    float4* sW4 = (float4*)sW;
#pragma unroll
    for (int i = 0; i < 8; ++i) sW4[i * 256 + tid] = W4[i * 256 + tid];
  }
  __syncthreads();
  int cg = tid & 3;
  int rp = tid >> 2;
  int r0 = blockIdx.x * 128 + rp * 2;
  int r1 = r0 + 1;
  bool v0 = (r0 < NN), v1 = (r1 < NN);
  int c0 = cg * 16;
  float4 a0[4], a1[4];
#pragma unroll
  for (int j = 0; j < 4; ++j) {
    a0[j] = make_float4(0.f, 0.f, 0.f, 0.f);
    a1[j] = make_float4(0.f, 0.f, 0.f, 0.f);
  }
  const float4* x4 = (const float4*)x;
  const float4 z4 = make_float4(0.f, 0.f, 0.f, 0.f);
  for (int k0 = 0; k0 < FIN; k0 += 4) {
    float4 xa = v0 ? x4[(size_t)r0 * 32 + (k0 >> 2)] : z4;
    float4 xb = v1 ? x4[(size_t)r1 * 32 + (k0 >> 2)] : z4;
#pragma unroll
    for (int kk = 0; kk < 4; ++kk) {
      float xav = (&xa.x)[kk];
      float xbv = (&xb.x)[kk];
      int k = k0 + kk;
#pragma unroll
      for (int j = 0; j < 4; ++j) {
        float4 wv = *(const float4*)&sW[k * HIDN + c0 + 4 * j];
        a0[j].x += xav * wv.x; a0[j].y += xav * wv.y;
        a0[j].z += xav * wv.z; a0[j].w += xav * wv.w;
        a1[j].x += xbv * wv.x; a1[j].y += xbv * wv.y;
        a1[j].z += xbv * wv.z; a1[j].w += xbv * wv.w;
      }
    }
  }
  if (v0) {
    float di = dinv[r0];
    uint4 q0, q1;
    q0.x = pack2(a0[0].x * di, a0[0].y * di); q0.y = pack2(a0[0].z * di, a0[0].w * di);
    q0.z = pack2(a0[1].x * di, a0[1].y * di); q0.w = pack2(a0[1].z * di, a0[1].w * di);
    q1.x = pack2(a0[2].x * di, a0[2].y * di); q1.y = pack2(a0[2].z * di, a0[2].w * di);
    q1.z = pack2(a0[3].x * di, a0[3].y * di); q1.w = pack2(a0[3].z * di, a0[3].w * di);
    uint4* hp = (uint4*)&hs[(size_t)r0 * 32 + cg * 8];
    hp[0] = q0; hp[1] = q1;
  }
  if (v1) {
    float di = dinv[r1];
    uint4 q0, q1;
    q0.x = pack2(a1[0].x * di, a1[0].y * di); q0.y = pack2(a1[0].z * di, a1[0].w * di);
    q0.z = pack2(a1[1].x * di, a1[1].y * di); q0.w = pack2(a1[1].z * di, a1[1].w * di);
    q1.x = pack2(a1[2].x * di, a1[2].y * di); q1.y = pack2(a1[2].z * di, a1[2].w * di);
    q1.z = pack2(a1[3].x * di, a1[3].y * di); q1.w = pack2(a1[3].z * di, a1[3].w * di);
    uint4* hp = (uint4*)&hs[(size_t)r1 * 32 + cg * 8];
    hp[0] = q0; hp[1] = q1;
  }
}

// ---- agg1: 16 lanes/edge, 4 edges/wave, unroll x2 -> 8 gathers in flight.
// g[n] = bf16( dinv_n * relu( dinv_n*(hs[n]+sum_j hs[s_j]) + b1 ) ) ----
__global__ __launch_bounds__(256) void agg1_kernel(const int* __restrict__ off,
                                                   const int* __restrict__ s_src,
                                                   const uint2* __restrict__ hs2,
                                                   const float* __restrict__ dinv,
                                                   const float* __restrict__ b1,
                                                   uint2* __restrict__ g) {
  int n = blockIdx.x * 4 + (threadIdx.x >> 6);     // NN = 25000*4 exactly
  int lane = threadIdx.x & 63;
  int q = lane >> 4;           // edge slot 0..3
  int hc = lane & 15;          // 4-col group (cols 4hc..4hc+3)
  int j0 = off[n], j1 = off[n + 1];
  float ax = 0.f, ay = 0.f, az = 0.f, aw = 0.f;
  if (q == 0) {
    uint2 v = hs2[(size_t)n * 16 + hc];
    ax = bf_lo(v.x); ay = bf_hi(v.x); az = bf_lo(v.y); aw = bf_hi(v.y);
  }
  int j = j0 + q;
  for (; j + 4 < j1; j += 8) {
    int sa = s_src[j], sb = s_src[j + 4];
    uint2 va = hs2[(size_t)sa * 16 + hc];
    uint2 vb = hs2[(size_t)sb * 16 + hc];
    ax += bf_lo(va.x); ay += bf_hi(va.x); az += bf_lo(va.y); aw += bf_hi(va.y);
    ax += bf_lo(vb.x); ay += bf_hi(vb.x); az += bf_lo(vb.y); aw += bf_hi(vb.y);
  }
  if (j < j1) {
    int sa = s_src[j];
    uint2 va = hs2[(size_t)sa * 16 + hc];
    ax += bf_lo(va.x); ay += bf_hi(va.x); az += bf_lo(va.y); aw += bf_hi(va.y);
  }
  ax += __shfl_xor(ax, 16, 64); ay += __shfl_xor(ay, 16, 64);
  az += __shfl_xor(az, 16, 64); aw += __shfl_xor(aw, 16, 64);
  ax += __shfl_xor(ax, 32, 64); ay += __shfl_xor(ay, 32, 64);
  az += __shfl_xor(az, 32, 64); aw += __shfl_xor(aw, 32, 64);
  if (q == 0) {
    float di = dinv[n];
    float4 bb = *(const float4*)&b1[hc * 4];
    float vx = di * fmaxf(ax * di + bb.x, 0.f);
    float vy = di * fmaxf(ay * di + bb.y, 0.f);
    float vz = di * fmaxf(az * di + bb.z, 0.f);
    float vw = di * fmaxf(aw * di + bb.w, 0.f);
    uint2 o;
    o.x = pack2(vx, vy);
    o.y = pack2(vz, vw);
    g[(size_t)n * 16 + hc] = o;   // 16 lanes x 8 B = 128 B contiguous
  }
}

// ---- agg2: same gather shape on g; t[n] = dinv_n*(g[n]+sum_j g[s_j]) (fp32) ----
__global__ __launch_bounds__(256) void agg2_kernel(const int* __restrict__ off,
                                                   const int* __restrict__ s_src,
                                                   const uint2* __restrict__ g,
                                                   const float* __restrict__ dinv,
                                                   float* __restrict__ t) {
  int n = blockIdx.x * 4 + (threadIdx.x >> 6);
  int lane = threadIdx.x & 63;
  int q = lane >> 4;
  int hc = lane & 15;
  int j0 = off[n], j1 = off[n + 1];
  float ax = 0.f, ay = 0.f, az = 0.f, aw = 0.f;
  if (q == 0) {
    uint2 v = g[(size_t)n * 16 + hc];
    ax = bf_lo(v.x); ay = bf_hi(v.x); az = bf_lo(v.y); aw = bf_hi(v.y);
  }
  int j = j0 + q;
  for (; j + 4 < j1; j += 8) {
    int sa = s_src[j], sb = s_src[j + 4];
    uint2 va = g[(size_t)sa * 16 + hc];
    uint2 vb = g[(size_t)sb * 16 + hc];
    ax += bf_lo(va.x); ay += bf_hi(va.x); az += bf_lo(va.y); aw += bf_hi(va.y);
    ax += bf_lo(vb.x); ay += bf_hi(vb.x); az += bf_lo(vb.y); aw += bf_hi(vb.y);
  }
  if (j < j1) {
    int sa = s_src[j];
    uint2 va = g[(size_t)sa * 16 + hc];
    ax += bf_lo(va.x); ay += bf_hi(va.x); az += bf_lo(va.y); aw += bf_hi(va.y);
  }
  ax += __shfl_xor(ax, 16, 64); ay += __shfl_xor(ay, 16, 64);
  az += __shfl_xor(az, 16, 64); aw += __shfl_xor(aw, 16, 64);
  ax += __shfl_xor(ax, 32, 64); ay += __shfl_xor(ay, 32, 64);
  az += __shfl_xor(az, 32, 64); aw += __shfl_xor(aw, 32, 64);
  if (q == 0) {
    float di = dinv[n];
    float4 o = make_float4(ax * di, ay * di, az * di, aw * di);
    *(float4*)&t[(size_t)n * HIDN + hc * 4] = o;  // 16 lanes x 16 B = 256 B
  }
}

// ---- mv: out[N,40] = t[N,64] @ W2[64,40] + b2 ----
// Low-pressure shape: 256 thr = 128 rows x 2 col-groups of 20. acc[20],
// t-row as 16 aligned float4 loads, sW reads are 2-distinct-address
// broadcasts (conflict-free). Replaces the 320-thr/2-row kernel that hit a
// register cliff (R3/R8: FETCH+WRITE ~1 GB, occ 12%, spill signature).
__global__ __launch_bounds__(256) void mv_kernel(const float* __restrict__ t,
                                                 const float* __restrict__ W2,
                                                 const float* __restrict__ b2,
                                                 float* __restrict__ out) {
  __shared__ float sW[HIDN * NCLS];  // 10 KB
  int tid = threadIdx.x;
  for (int i = tid; i < (HIDN * NCLS) / 4; i += 256)
    ((float4*)sW)[i] = ((const float4*)W2)[i];
  __syncthreads();
  int cg = tid & 1;
  int r = blockIdx.x * 128 + (tid >> 1);
  if (r >= NN) return;
  int c0 = cg * 20;
  float acc[20];
#pragma unroll
  for (int j = 0; j < 20; ++j) acc[j] = b2[c0 + j];
  const float4* t4 = (const float4*)(t + (size_t)r * HIDN);
#pragma unroll 4
  for (int k4 = 0; k4 < 16; ++k4) {
    float4 tv = t4[k4];
#pragma unroll
    for (int kk = 0; kk < 4; ++kk) {
      float xv = (&tv.x)[kk];
      const float* wr = &sW[(k4 * 4 + kk) * NCLS + c0];
#pragma unroll
      for (int j = 0; j < 5; ++j) {
        float4 wv = *(const float4*)&wr[j * 4];
        acc[j * 4 + 0] = fmaf(xv, wv.x, acc[j * 4 + 0]);
        acc[j * 4 + 1] = fmaf(xv, wv.y, acc[j * 4 + 1]);
        acc[j * 4 + 2] = fmaf(xv, wv.z, acc[j * 4 + 2]);
        acc[j * 4 + 3] = fmaf(xv, wv.w, acc[j * 4 + 3]);
      }
    }
  }
  float4* op = (float4*)&out[(size_t)r * NCLS + c0];
#pragma unroll
  for (int j = 0; j < 5; ++j)
    op[j] = make_float4(acc[j * 4 + 0], acc[j * 4 + 1],
                        acc[j * 4 + 2], acc[j * 4 + 3]);
}

extern "C" void kernel_launch(void* const* d_in, const int* in_sizes, int n_in,
                              void* d_out, int out_size, void* d_ws, size_t ws_size,
                              hipStream_t stream) {
  const float* x  = (const float*)d_in[0];
  const void*  ei = d_in[1];
  const float* W1 = (const float*)d_in[2];
  const float* b1 = (const float*)d_in[3];
  const float* W2 = (const float*)d_in[4];
  const float* b2 = (const float*)d_in[5];
  float* out = (float*)d_out;

  char* w = (char*)d_ws;
  size_t off_b = 0;
  auto carve = [&](size_t bytes) -> void* {
    void* p = w + off_b;
    off_b = (off_b + bytes + 255) & ~(size_t)255;
    return p;
  };
  int*    mat   = (int*)   carve((size_t)NEB * NBUCK * 4);   // 611 KB
  int*    tot   = (int*)   carve((size_t)NBUCK * 4);
  int*    bbase = (int*)   carve((size_t)(NBUCK + 1) * 4);
  int*    offs  = (int*)   carve((size_t)(NN + 1) * 4);
  float*  dinv  = (float*) carve((size_t)NN * 4);
  int*    flag  = (int*)   carve(256);
  int*    s_src = (int*)   carve((size_t)NE * 4);
  uint32* hs    = (uint32*)carve((size_t)NN * 32 * 4);       // bf16 h, 12.8 MB
  uint2*  g     = (uint2*) carve((size_t)NN * 16 * 8);       // bf16 g, 12.8 MB
  float*  t     = (float*) carve((size_t)NN * HIDN * 4);     // fp32, 25.6 MB
  uint32* bbuf  = (uint32*)carve((size_t)NE * 4);            // 6.4 MB (own carve)

  probe_kernel<<<1, 64, 0, stream>>>((const unsigned int*)ei, flag);
  passA_kernel<<<NEB, 256, 0, stream>>>(ei, flag, mat);
  passB1_kernel<<<NBUCK, 512, 0, stream>>>(mat, tot);
  passB2_kernel<<<1, 512, 0, stream>>>(tot, bbase);
  passC_kernel<<<NEB, 256, 0, stream>>>(ei, flag, mat, bbase, bbuf);
  build_kernel<<<NBUCK, 256, 0, stream>>>(bbase, bbuf, offs, dinv, s_src);
  gemm1_kernel<<<(NN + 127) / 128, 256, 0, stream>>>(x, W1, dinv, hs);
  agg1_kernel<<<NN / 4, 256, 0, stream>>>(offs, s_src, (const uint2*)hs, dinv, b1, g);
  agg2_kernel<<<NN / 4, 256, 0, stream>>>(offs, s_src, g, dinv, t);
  mv_kernel<<<(NN + 127) / 128, 256, 0, stream>>>(t, W2, b2, out);
}

// Round 10
// 287.082 us; speedup vs baseline: 2.3572x; 1.0224x over previous
//
#include <hip/hip_runtime.h>
#include <stdint.h>

#define NN    100000
#define FIN   128
#define HIDN  64
#define NCLS  40
#define NE    1600000
#define NBUCK ((NN + 255) / 256)      // 391 buckets of 256 nodes
#define EPB   4096                    // edges per partition block
#define NEB   ((NE + EPB - 1) / EPB)  // 391 partition blocks

typedef unsigned int uint32;

static __device__ __forceinline__ unsigned short f2bf(float f) {
  uint32 u = __float_as_uint(f);
  u = (u + 0x7fffu + ((u >> 16) & 1u)) >> 16;   // RNE
  return (unsigned short)u;
}
static __device__ __forceinline__ uint32 pack2(float lo, float hi) {
  return (uint32)f2bf(lo) | ((uint32)f2bf(hi) << 16);
}
static __device__ __forceinline__ float bf_lo(uint32 v) {
  return __uint_as_float(v << 16);
}
static __device__ __forceinline__ float bf_hi(uint32 v) {
  return __uint_as_float(v & 0xFFFF0000u);
}

// ---- edge dtype probe: int64 (odd u32 words all zero) vs int32 ----
__global__ __launch_bounds__(64) void probe_kernel(const unsigned int* __restrict__ raw,
                                                   int* __restrict__ flag) {
  if (threadIdx.x == 0) {
    int is64 = 1;
    for (int i = 0; i < 64; ++i)
      if (raw[2 * i + 1] != 0u) { is64 = 0; break; }
    *flag = is64;
  }
}

// ---- passA: per-block bucket histogram -> mat[blk][bucket] ----
__global__ __launch_bounds__(256) void passA_kernel(const void* __restrict__ eptr,
                                                    const int* __restrict__ flag,
                                                    int* __restrict__ mat) {
  __shared__ int cnt[NBUCK];
  int tid = threadIdx.x;
  for (int i = tid; i < NBUCK; i += 256) cnt[i] = 0;
  __syncthreads();
  int is64 = *flag;
  int base = blockIdx.x * EPB;
#pragma unroll
  for (int k = 0; k < EPB / 256; ++k) {
    int e = base + k * 256 + tid;
    if (e < NE) {
      int d = is64 ? (int)((const long long*)eptr)[e + NE]
                   : ((const int*)eptr)[e + NE];
      atomicAdd(&cnt[d >> 8], 1);
    }
  }
  __syncthreads();
  for (int i = tid; i < NBUCK; i += 256)
    mat[blockIdx.x * NBUCK + i] = cnt[i];
}

// ---- passB1: per-bucket exclusive scan over blocks; emit bucket totals ----
__global__ __launch_bounds__(512) void passB1_kernel(int* __restrict__ mat,
                                                     int* __restrict__ tot) {
  __shared__ int s[512];
  int b = blockIdx.x;         // bucket
  int t = threadIdx.x;        // block index
  int v = (t < NEB) ? mat[t * NBUCK + b] : 0;
  s[t] = v;
  __syncthreads();
#pragma unroll
  for (int d = 1; d < 512; d <<= 1) {
    int u = (t >= d) ? s[t - d] : 0;
    __syncthreads();
    s[t] += u;
    __syncthreads();
  }
  if (t < NEB) mat[t * NBUCK + b] = s[t] - v;  // exclusive prefix within bucket
  if (t == 511) tot[b] = s[511];
}

// ---- passB2: exclusive scan of bucket totals -> bbase ----
__global__ __launch_bounds__(512) void passB2_kernel(const int* __restrict__ tot,
                                                     int* __restrict__ bbase) {
  __shared__ int s[512];
  int i = threadIdx.x;
  int v = (i < NBUCK) ? tot[i] : 0;
  s[i] = v;
  __syncthreads();
#pragma unroll
  for (int d = 1; d < 512; d <<= 1) {
    int u = (i >= d) ? s[i - d] : 0;
    __syncthreads();
    s[i] += u;
    __syncthreads();
  }
  if (i < NBUCK) bbase[i] = s[i] - v;
  if (i == 511) bbase[NBUCK] = s[511];
}

// ---- passC: place edges into compact bucket-sorted bbuf (LDS cursors) ----
__global__ __launch_bounds__(256) void passC_kernel(const void* __restrict__ eptr,
                                                    const int* __restrict__ flag,
                                                    const int* __restrict__ mat,
                                                    const int* __restrict__ bbase,
                                                    uint32* __restrict__ bbuf) {
  __shared__ int cur[NBUCK];
  int tid = threadIdx.x;
  for (int i = tid; i < NBUCK; i += 256)
    cur[i] = bbase[i] + mat[blockIdx.x * NBUCK + i];
  __syncthreads();
  int is64 = *flag;
  int base = blockIdx.x * EPB;
#pragma unroll
  for (int k = 0; k < EPB / 256; ++k) {
    int e = base + k * 256 + tid;
    if (e < NE) {
      int s, d;
      if (is64) {
        const long long* p = (const long long*)eptr;
        s = (int)p[e]; d = (int)p[e + NE];
      } else {
        const int* p = (const int*)eptr;
        s = p[e]; d = p[e + NE];
      }
      int slot = atomicAdd(&cur[d >> 8], 1);
      bbuf[slot] = (uint32)s | ((uint32)(d & 255) << 17);
    }
  }
}

// ---- build: per-bucket CSR (LDS hist + scan + rank placement) ----
__global__ __launch_bounds__(256) void build_kernel(const int* __restrict__ bbase,
                                                    const uint32* __restrict__ bbuf,
                                                    int* __restrict__ off,
                                                    float* __restrict__ dinv,
                                                    int* __restrict__ s_src) {
  __shared__ int hist[256];
  __shared__ int lofs[256];
  __shared__ int rank[256];
  int b = blockIdx.x, tid = threadIdx.x;
  int base = bbase[b];
  int count = bbase[b + 1] - base;
  const uint32* p = bbuf + base;
  hist[tid] = 0;
  __syncthreads();
  for (int i = tid; i < count; i += 256) atomicAdd(&hist[p[i] >> 17], 1);
  __syncthreads();
  int deg = hist[tid];
  lofs[tid] = deg;
  __syncthreads();
#pragma unroll
  for (int dd = 1; dd < 256; dd <<= 1) {
    int t = (tid >= dd) ? lofs[tid - dd] : 0;
    __syncthreads();
    lofs[tid] += t;
    __syncthreads();
  }
  int excl = lofs[tid] - deg;
  __syncthreads();
  lofs[tid] = excl;
  rank[tid] = 0;
  int n = b * 256 + tid;
  if (n < NN) {
    off[n] = base + excl;
    dinv[n] = rsqrtf((float)deg + 1.0f);
  }
  if (b == 0 && tid == 0) off[NN] = NE;
  __syncthreads();
  for (int i = tid; i < count; i += 256) {
    uint32 v = p[i];
    int dl = (int)(v >> 17);
    int s = (int)(v & 0x1FFFFu);
    int r = atomicAdd(&rank[dl], 1);
    s_src[base + lofs[dl] + r] = s;
  }
}

// ---- GEMM1: hs[N,64](bf16) = (x[N,128] @ W1[128,64]) * dinv[row] ----
// 4 rows/thread: each ds_read_b128 of W feeds 4 rows (halves LDS-pipe load
// vs the 2-row shape that measured LDS-bound at 53 us in R9).
__global__ __launch_bounds__(256) void gemm1_kernel(const float* __restrict__ x,
                                                    const float* __restrict__ W,
                                                    const float* __restrict__ dinv,
                                                    uint32* __restrict__ hs) {
  __shared__ float sW[FIN * HIDN];  // 32 KB
  int tid = threadIdx.x;
  {
    const float4* W4 = (const float4*)W;
    float4* sW4 = (float4*)sW;
#pragma unroll
    for (int i = 0; i < 8; ++i) sW4[i * 256 + tid] = W4[i * 256 + tid];
  }
  __syncthreads();
  int cg = tid & 3;            // 4 col groups of 16
  int rp = tid >> 2;           // 64 row groups of 4 rows
  int r0 = blockIdx.x * 256 + rp * 4;
  int c0 = cg * 16;
  bool v[4];
#pragma unroll
  for (int r = 0; r < 4; ++r) v[r] = (r0 + r) < NN;
  float4 acc[4][4];            // [row][col quad]
#pragma unroll
  for (int r = 0; r < 4; ++r)
#pragma unroll
    for (int j = 0; j < 4; ++j) acc[r][j] = make_float4(0.f, 0.f, 0.f, 0.f);
  const float4* x4 = (const float4*)x;
  const float4 z4 = make_float4(0.f, 0.f, 0.f, 0.f);
  for (int k0 = 0; k0 < FIN; k0 += 4) {
    float4 xr[4];
#pragma unroll
    for (int r = 0; r < 4; ++r)
      xr[r] = v[r] ? x4[(size_t)(r0 + r) * 32 + (k0 >> 2)] : z4;
#pragma unroll
    for (int kk = 0; kk < 4; ++kk) {
#pragma unroll
      for (int j = 0; j < 4; ++j) {
        float4 wv = *(const float4*)&sW[(k0 + kk) * HIDN + c0 + 4 * j];
#pragma unroll
        for (int r = 0; r < 4; ++r) {
          float xv = (&xr[r].x)[kk];
          acc[r][j].x = fmaf(xv, wv.x, acc[r][j].x);
          acc[r][j].y = fmaf(xv, wv.y, acc[r][j].y);
          acc[r][j].z = fmaf(xv, wv.z, acc[r][j].z);
          acc[r][j].w = fmaf(xv, wv.w, acc[r][j].w);
        }
      }
    }
  }
#pragma unroll
  for (int r = 0; r < 4; ++r) {
    if (!v[r]) continue;
    float di = dinv[r0 + r];
    uint4 q0, q1;
    q0.x = pack2(acc[r][0].x * di, acc[r][0].y * di);
    q0.y = pack2(acc[r][0].z * di, acc[r][0].w * di);
    q0.z = pack2(acc[r][1].x * di, acc[r][1].y * di);
    q0.w = pack2(acc[r][1].z * di, acc[r][1].w * di);
    q1.x = pack2(acc[r][2].x * di, acc[r][2].y * di);
    q1.y = pack2(acc[r][2].z * di, acc[r][2].w * di);
    q1.z = pack2(acc[r][3].x * di, acc[r][3].y * di);
    q1.w = pack2(acc[r][3].z * di, acc[r][3].w * di);
    uint4* hp = (uint4*)&hs[(size_t)(r0 + r) * 32 + cg * 8];
    hp[0] = q0; hp[1] = q1;
  }
}

// ---- agg1: 8 lanes/edge (uint4=16B), 8 edge slots/wave, unroll x2 ->
// 16 gathers in flight. g[n] = bf16(dinv_n*relu(dinv_n*(hs[n]+sum)+b1)) ----
__global__ __launch_bounds__(256) void agg1_kernel(const int* __restrict__ off,
                                                   const int* __restrict__ s_src,
                                                   const uint4* __restrict__ hs4,
                                                   const float* __restrict__ dinv,
                                                   const float* __restrict__ b1,
                                                   uint4* __restrict__ g) {
  int n = blockIdx.x * 4 + (threadIdx.x >> 6);     // NN = 25000*4 exactly
  int lane = threadIdx.x & 63;
  int q = lane >> 3;           // edge slot 0..7
  int hc = lane & 7;           // 8-col chunk (cols 8hc..8hc+7)
  int j0 = off[n], j1 = off[n + 1];
  float a[8];
#pragma unroll
  for (int i = 0; i < 8; ++i) a[i] = 0.f;
  if (q == 0) {
    uint4 v = hs4[(size_t)n * 8 + hc];
    a[0] = bf_lo(v.x); a[1] = bf_hi(v.x); a[2] = bf_lo(v.y); a[3] = bf_hi(v.y);
    a[4] = bf_lo(v.z); a[5] = bf_hi(v.z); a[6] = bf_lo(v.w); a[7] = bf_hi(v.w);
  }
  int j = j0 + q;
  for (; j + 8 < j1; j += 16) {
    int sa = s_src[j], sb = s_src[j + 8];
    uint4 va = hs4[(size_t)sa * 8 + hc];
    uint4 vb = hs4[(size_t)sb * 8 + hc];
    a[0] += bf_lo(va.x); a[1] += bf_hi(va.x); a[2] += bf_lo(va.y); a[3] += bf_hi(va.y);
    a[4] += bf_lo(va.z); a[5] += bf_hi(va.z); a[6] += bf_lo(va.w); a[7] += bf_hi(va.w);
    a[0] += bf_lo(vb.x); a[1] += bf_hi(vb.x); a[2] += bf_lo(vb.y); a[3] += bf_hi(vb.y);
    a[4] += bf_lo(vb.z); a[5] += bf_hi(vb.z); a[6] += bf_lo(vb.w); a[7] += bf_hi(vb.w);
  }
  if (j < j1) {
    int sa = s_src[j];
    uint4 va = hs4[(size_t)sa * 8 + hc];
    a[0] += bf_lo(va.x); a[1] += bf_hi(va.x); a[2] += bf_lo(va.y); a[3] += bf_hi(va.y);
    a[4] += bf_lo(va.z); a[5] += bf_hi(va.z); a[6] += bf_lo(va.w); a[7] += bf_hi(va.w);
  }
#pragma unroll
  for (int i = 0; i < 8; ++i) {
    a[i] += __shfl_xor(a[i], 8, 64);
    a[i] += __shfl_xor(a[i], 16, 64);
    a[i] += __shfl_xor(a[i], 32, 64);
  }
  if (q == 0) {
    float di = dinv[n];
    float4 b0 = *(const float4*)&b1[hc * 8];
    float4 b4 = *(const float4*)&b1[hc * 8 + 4];
    float r0 = di * fmaxf(a[0] * di + b0.x, 0.f);
    float r1 = di * fmaxf(a[1] * di + b0.y, 0.f);
    float r2 = di * fmaxf(a[2] * di + b0.z, 0.f);
    float r3 = di * fmaxf(a[3] * di + b0.w, 0.f);
    float r4 = di * fmaxf(a[4] * di + b4.x, 0.f);
    float r5 = di * fmaxf(a[5] * di + b4.y, 0.f);
    float r6 = di * fmaxf(a[6] * di + b4.z, 0.f);
    float r7 = di * fmaxf(a[7] * di + b4.w, 0.f);
    uint4 o;
    o.x = pack2(r0, r1); o.y = pack2(r2, r3);
    o.z = pack2(r4, r5); o.w = pack2(r6, r7);
    g[(size_t)n * 8 + hc] = o;    // 8 lanes x 16 B = 128 B contiguous
  }
}

// ---- agg2: same gather shape on g; t[n] = dinv_n*(g[n]+sum_j g[s_j]) (fp32) ----
__global__ __launch_bounds__(256) void agg2_kernel(const int* __restrict__ off,
                                                   const int* __restrict__ s_src,
                                                   const uint4* __restrict__ g,
                                                   const float* __restrict__ dinv,
                                                   float* __restrict__ t) {
  int n = blockIdx.x * 4 + (threadIdx.x >> 6);
  int lane = threadIdx.x & 63;
  int q = lane >> 3;
  int hc = lane & 7;
  int j0 = off[n], j1 = off[n + 1];
  float a[8];
#pragma unroll
  for (int i = 0; i < 8; ++i) a[i] = 0.f;
  if (q == 0) {
    uint4 v = g[(size_t)n * 8 + hc];
    a[0] = bf_lo(v.x); a[1] = bf_hi(v.x); a[2] = bf_lo(v.y); a[3] = bf_hi(v.y);
    a[4] = bf_lo(v.z); a[5] = bf_hi(v.z); a[6] = bf_lo(v.w); a[7] = bf_hi(v.w);
  }
  int j = j0 + q;
  for (; j + 8 < j1; j += 16) {
    int sa = s_src[j], sb = s_src[j + 8];
    uint4 va = g[(size_t)sa * 8 + hc];
    uint4 vb = g[(size_t)sb * 8 + hc];
    a[0] += bf_lo(va.x); a[1] += bf_hi(va.x); a[2] += bf_lo(va.y); a[3] += bf_hi(va.y);
    a[4] += bf_lo(va.z); a[5] += bf_hi(va.z); a[6] += bf_lo(va.w); a[7] += bf_hi(va.w);
    a[0] += bf_lo(vb.x); a[1] += bf_hi(vb.x); a[2] += bf_lo(vb.y); a[3] += bf_hi(vb.y);
    a[4] += bf_lo(vb.z); a[5] += bf_hi(vb.z); a[6] += bf_lo(vb.w); a[7] += bf_hi(vb.w);
  }
  if (j < j1) {
    int sa = s_src[j];
    uint4 va = g[(size_t)sa * 8 + hc];
    a[0] += bf_lo(va.x); a[1] += bf_hi(va.x); a[2] += bf_lo(va.y); a[3] += bf_hi(va.y);
    a[4] += bf_lo(va.z); a[5] += bf_hi(va.z); a[6] += bf_lo(va.w); a[7] += bf_hi(va.w);
  }
#pragma unroll
  for (int i = 0; i < 8; ++i) {
    a[i] += __shfl_xor(a[i], 8, 64);
    a[i] += __shfl_xor(a[i], 16, 64);
    a[i] += __shfl_xor(a[i], 32, 64);
  }
  if (q == 0) {
    float di = dinv[n];
    float* tp = &t[(size_t)n * HIDN + hc * 8];
    *(float4*)tp = make_float4(a[0] * di, a[1] * di, a[2] * di, a[3] * di);
    *(float4*)(tp + 4) = make_float4(a[4] * di, a[5] * di, a[6] * di, a[7] * di);
  }
}

// ---- mv: out[N,40] = t[N,64] @ W2[64,40] + b2 ----
// Low-pressure shape (R9-proven): 256 thr = 128 rows x 2 col-groups of 20.
__global__ __launch_bounds__(256) void mv_kernel(const float* __restrict__ t,
                                                 const float* __restrict__ W2,
                                                 const float* __restrict__ b2,
                                                 float* __restrict__ out) {
  __shared__ float sW[HIDN * NCLS];  // 10 KB
  int tid = threadIdx.x;
  for (int i = tid; i < (HIDN * NCLS) / 4; i += 256)
    ((float4*)sW)[i] = ((const float4*)W2)[i];
  __syncthreads();
  int cg = tid & 1;
  int r = blockIdx.x * 128 + (tid >> 1);
  if (r >= NN) return;
  int c0 = cg * 20;
  float acc[20];
#pragma unroll
  for (int j = 0; j < 20; ++j) acc[j] = b2[c0 + j];
  const float4* t4 = (const float4*)(t + (size_t)r * HIDN);
#pragma unroll 4
  for (int k4 = 0; k4 < 16; ++k4) {
    float4 tv = t4[k4];
#pragma unroll
    for (int kk = 0; kk < 4; ++kk) {
      float xv = (&tv.x)[kk];
      const float* wr = &sW[(k4 * 4 + kk) * NCLS + c0];
#pragma unroll
      for (int j = 0; j < 5; ++j) {
        float4 wv = *(const float4*)&wr[j * 4];
        acc[j * 4 + 0] = fmaf(xv, wv.x, acc[j * 4 + 0]);
        acc[j * 4 + 1] = fmaf(xv, wv.y, acc[j * 4 + 1]);
        acc[j * 4 + 2] = fmaf(xv, wv.z, acc[j * 4 + 2]);
        acc[j * 4 + 3] = fmaf(xv, wv.w, acc[j * 4 + 3]);
      }
    }
  }
  float4* op = (float4*)&out[(size_t)r * NCLS + c0];
#pragma unroll
  for (int j = 0; j < 5; ++j)
    op[j] = make_float4(acc[j * 4 + 0], acc[j * 4 + 1],
                        acc[j * 4 + 2], acc[j * 4 + 3]);
}

extern "C" void kernel_launch(void* const* d_in, const int* in_sizes, int n_in,
                              void* d_out, int out_size, void* d_ws, size_t ws_size,
                              hipStream_t stream) {
  const float* x  = (const float*)d_in[0];
  const void*  ei = d_in[1];
  const float* W1 = (const float*)d_in[2];
  const float* b1 = (const float*)d_in[3];
  const float* W2 = (const float*)d_in[4];
  const float* b2 = (const float*)d_in[5];
  float* out = (float*)d_out;

  char* w = (char*)d_ws;
  size_t off_b = 0;
  auto carve = [&](size_t bytes) -> void* {
    void* p = w + off_b;
    off_b = (off_b + bytes + 255) & ~(size_t)255;
    return p;
  };
  int*    mat   = (int*)   carve((size_t)NEB * NBUCK * 4);   // 611 KB
  int*    tot   = (int*)   carve((size_t)NBUCK * 4);
  int*    bbase = (int*)   carve((size_t)(NBUCK + 1) * 4);
  int*    offs  = (int*)   carve((size_t)(NN + 1) * 4);
  float*  dinv  = (float*) carve((size_t)NN * 4);
  int*    flag  = (int*)   carve(256);
  int*    s_src = (int*)   carve((size_t)NE * 4);
  uint32* hs    = (uint32*)carve((size_t)NN * 32 * 4);       // bf16 h, 12.8 MB
  uint4*  g     = (uint4*) carve((size_t)NN * 8 * 16);       // bf16 g, 12.8 MB
  float*  t     = (float*) carve((size_t)NN * HIDN * 4);     // fp32, 25.6 MB
  uint32* bbuf  = (uint32*)carve((size_t)NE * 4);            // 6.4 MB

  probe_kernel<<<1, 64, 0, stream>>>((const unsigned int*)ei, flag);
  passA_kernel<<<NEB, 256, 0, stream>>>(ei, flag, mat);
  passB1_kernel<<<NBUCK, 512, 0, stream>>>(mat, tot);
  passB2_kernel<<<1, 512, 0, stream>>>(tot, bbase);
  passC_kernel<<<NEB, 256, 0, stream>>>(ei, flag, mat, bbase, bbuf);
  build_kernel<<<NBUCK, 256, 0, stream>>>(bbase, bbuf, offs, dinv, s_src);
  gemm1_kernel<<<(NN + 255) / 256, 256, 0, stream>>>(x, W1, dinv, hs);
  agg1_kernel<<<NN / 4, 256, 0, stream>>>(offs, s_src, (const uint4*)hs, dinv, b1, g);
  agg2_kernel<<<NN / 4, 256, 0, stream>>>(offs, s_src, g, dinv, t);
  mv_kernel<<<(NN + 127) / 128, 256, 0, stream>>>(t, W2, b2, out);
}